// Round 8
// baseline (452.422 us; speedup 1.0000x reference)
//
#include <hip/hip_runtime.h>

typedef __bf16 bf16x8 __attribute__((ext_vector_type(8)));
typedef float  f32x4  __attribute__((ext_vector_type(4)));

__device__ __forceinline__ unsigned short f2bf(float x){
  return __builtin_bit_cast(unsigned short, (__bf16)x);   // HW v_cvt on gfx950, RNE
}

// LDS-only barrier: all our inter-wave hazards are LDS ping-pong buffers, so
// wait lgkmcnt(0) only — do NOT drain vmcnt (keeps trg prefetch + out[] store
// acks in flight across the barrier, unlike __syncthreads()).
__device__ __forceinline__ void bar_lds(){
  asm volatile("s_waitcnt lgkmcnt(0)" ::: "memory");
  __builtin_amdgcn_s_barrier();
  asm volatile("" ::: "memory");
}

// ---------------------------------------------------------------------------
// Weight pack: MFMA B-fragment order (bf16), lane holds B[k=kt*32+(lane>>4)*8+jj][n=lane&15].
// Gate weights PRE-SCALED by -log2(e) (i,f,o) or -2*log2(e) (g) so the MFMA
// accumulator is directly the exp2() argument.
// Frag sections: [0,48) encL0 (ntile*3+kt, K: x 0..16|pad|h 32..96)
//                [48,112) encL1 (ntile*4+kt, K: h0 0..64|h1 64..128)
//                [112,160) decL0, [160,224) decL1, [224,226) W_out (N=4 padded to 16, K=64)
// ---------------------------------------------------------------------------
__global__ void pack_weights(const float* __restrict__ eWih0, const float* __restrict__ eWhh0,
                             const float* __restrict__ eWih1, const float* __restrict__ eWhh1,
                             const float* __restrict__ dWih0, const float* __restrict__ dWhh0,
                             const float* __restrict__ dWih1, const float* __restrict__ dWhh1,
                             const float* __restrict__ Wout,
                             unsigned short* __restrict__ out){
  int t = blockIdx.x * 256 + threadIdx.x;
  if (t >= 226 * 64) return;
  int lane = t & 63;
  int f    = t >> 6;
  unsigned short vals[8];
  if (f >= 224){                                       // W_out frags (NOT scaled)
    int kt = f - 224, n = lane & 15;
#pragma unroll
    for (int jj = 0; jj < 8; jj++){
      int k = kt * 32 + (lane >> 4) * 8 + jj;
      vals[jj] = (n < 4) ? f2bf(Wout[n * 64 + k]) : (unsigned short)0;
    }
  } else {
    const float *Wih, *Whh; int kx, ntile, kt;
    if (f < 48)       { Wih=eWih0; Whh=eWhh0; kx=16; ntile=f/3;        kt=f%3; }
    else if (f < 112) { Wih=eWih1; Whh=eWhh1; kx=64; ntile=(f-48)/4;   kt=(f-48)%4; }
    else if (f < 160) { Wih=dWih0; Whh=dWhh0; kx=16; ntile=(f-112)/3;  kt=(f-112)%3; }
    else              { Wih=dWih1; Whh=dWhh1; kx=64; ntile=(f-160)/4;  kt=(f-160)%4; }
    int n    = ntile * 16 + (lane & 15);
    int hoff = (kx == 16) ? 32 : 64;
    // gate index = n/64 = ntile/4; gates i,f,o get -log2(e), gate g gets -2*log2(e)
    float scale = ((ntile >> 2) == 2) ? -2.88539008f : -1.44269504f;
#pragma unroll
    for (int jj = 0; jj < 8; jj++){
      int k = kt * 32 + (lane >> 4) * 8 + jj;
      float v;
      if (k < kx)        v = Wih[n * kx + k];
      else if (k < hoff) v = 0.0f;
      else               v = Whh[n * 64 + (k - hoff)];
      vals[jj] = f2bf(v * scale);
    }
  }
  uint4 o;
  o.x = (unsigned)vals[0] | ((unsigned)vals[1] << 16);
  o.y = (unsigned)vals[2] | ((unsigned)vals[3] << 16);
  o.z = (unsigned)vals[4] | ((unsigned)vals[5] << 16);
  o.w = (unsigned)vals[6] | ((unsigned)vals[7] << 16);
  ((uint4*)out)[f * 64 + lane] = o;
}

// A-layout (per 16-row subtile): elem(m,k) at ((k>>5)*64 + (m | (((k>>3)&3)<<4)))*8 + (k&7)
__device__ __forceinline__ void write_h(unsigned short* buf, int k, int quad,
                                        const unsigned short* h){
  unsigned short* p = buf + (((k >> 5) * 64) + quad * 4 + (((k >> 3) & 3) << 4)) * 8 + (k & 7);
#pragma unroll
  for (int e = 0; e < 4; e++) p[e * 8] = h[e];
}

__device__ __forceinline__ void load_frags(const unsigned short* __restrict__ pw,
                                           int base0, int base1, int w, int lane,
                                           bf16x8 (&B0)[3][4], bf16x8 (&B1)[4][4]){
#pragma unroll
  for (int g = 0; g < 4; g++){
    int nt = 4 * g + w;
#pragma unroll
    for (int kt = 0; kt < 3; kt++)
      B0[kt][g] = *(const bf16x8*)(pw + (((long)(base0 + nt * 3 + kt)) * 64 + lane) * 8);
#pragma unroll
    for (int kt = 0; kt < 4; kt++)
      B1[kt][g] = *(const bf16x8*)(pw + (((long)(base1 + nt * 4 + kt)) * 64 + lane) * 8);
  }
}

// One LSTM cell step for 32 rows (2 row-subtiles of 16, interleaved: 8 indep
// MFMA chains), this wave's 16 j's. acc arrives exp2-ready (pre-scaled weights).
// Single-rcp c-update (common denominator):
//   c2 = [c*(1+ei)(1+eg) + K(1-eg)(1+ef)] / [(1+ef)(1+ei)(1+eg)],  K = 2*log2(e)
//   sig(o)*tanh(c) = (ec-1)/((1+eo)(1+ec)),  ec = exp2(c2) = e^{2c}
template<int KT, int SZ>
__device__ __forceinline__ void cell_compute(const unsigned short* __restrict__ A,
                                             const bf16x8 (&B)[KT][4],
                                             const float (&bias)[4],
                                             float (&c)[8],
                                             unsigned short (&hout)[8],
                                             int lane){
  f32x4 acc[4][2];
#pragma unroll
  for (int g = 0; g < 4; g++){
    f32x4 b = {bias[g], bias[g], bias[g], bias[g]};
    acc[g][0] = b; acc[g][1] = b;
  }
#pragma unroll
  for (int kt = 0; kt < KT; kt++){
    bf16x8 a0 = *(const bf16x8*)(A +      (kt * 64 + lane) * 8);
    bf16x8 a1 = *(const bf16x8*)(A + SZ + (kt * 64 + lane) * 8);
#pragma unroll
    for (int g = 0; g < 4; g++){
      acc[g][0] = __builtin_amdgcn_mfma_f32_16x16x32_bf16(a0, B[kt][g], acc[g][0], 0, 0, 0);
      acc[g][1] = __builtin_amdgcn_mfma_f32_16x16x32_bf16(a1, B[kt][g], acc[g][1], 0, 0, 0);
    }
  }
#pragma unroll
  for (int rt = 0; rt < 2; rt++){
#pragma unroll
    for (int e = 0; e < 4; e++){
      int idx = rt * 4 + e;
      float ei = __builtin_amdgcn_exp2f(acc[0][rt][e]);   // e^{-i}
      float ef = __builtin_amdgcn_exp2f(acc[1][rt][e]);   // e^{-f}
      float eg = __builtin_amdgcn_exp2f(acc[2][rt][e]);   // e^{-2g}
      float eo = __builtin_amdgcn_exp2f(acc[3][rt][e]);   // e^{-o}
      float pf   = 1.0f + ef;
      float pig  = (1.0f + ei) * (1.0f + eg);
      float rden = __builtin_amdgcn_rcpf(pf * pig);
      float num  = fmaf(fmaf(-2.88539008f, eg, 2.88539008f), pf, c[idx] * pig);
      float c2   = num * rden;
      c[idx] = c2;
      float ec  = __builtin_amdgcn_exp2f(c2);             // e^{2c}
      float rot = __builtin_amdgcn_rcpf((1.0f + eo) * (1.0f + ec));
      hout[idx] = f2bf((ec - 1.0f) * rot);                // sig(o)*tanh(c)
    }
  }
}

// ---------------------------------------------------------------------------
// Main: one block = 32 batch rows. Encoder: 1 barrier/step (layer-skewed).
// Decoder: 3 barriers/step — the proj waves (w<2) compute the NEXT step's
// m-projection in-register (16 ds_bpermute gather + 16 fma, reusing each
// lane's wv=W_in[l16]/bin) and write A0[nxt] m-slots directly; the xfb
// round-trip barrier is gone. All barriers LDS-only (bar_lds).
// ---------------------------------------------------------------------------
__global__ __launch_bounds__(256, 2)
void lstm_main(const float* __restrict__ src, const float* __restrict__ trg,
               const float* __restrict__ W_in, const float* __restrict__ b_in,
               const float* __restrict__ eb0, const float* __restrict__ eb1,
               const float* __restrict__ db0, const float* __restrict__ db1,
               const float* __restrict__ bout,
               const unsigned short* __restrict__ pw,
               float* __restrict__ out){
  __shared__ __align__(16) unsigned short A0[2][2][1536];   // ping-pong, 2 row-subtiles, K=96
  __shared__ __align__(16) unsigned short A1[2][2][2048];   // K=128
  __shared__ __align__(16) float xsrc[2][128];              // encoder x ping-pong (32 rows x 4)
  __shared__ __align__(16) unsigned short sWoutF[1024];     // W_out B-frags (2 x 64 x 8)

  const int tid  = threadIdx.x;
  const int lane = tid & 63;
  const int w    = tid >> 6;
  const int quad = lane >> 4;
  const int l16  = lane & 15;
  const int j    = 16 * w + l16;
  const int rowg0 = blockIdx.x * 32;
  const int mm   = tid & 15;                  // x-proj: this thread's m-unit (== l16)
  const int xr   = tid >> 4;                  // x-proj: rows xr and xr+16

  // ---- staging ----
  {
    uint4 z; z.x = z.y = z.z = z.w = 0u;
    uint4* a0p = (uint4*)A0;                  // 768 uint4
    uint4* a1p = (uint4*)A1;                  // 1024 uint4
    for (int i = tid; i < 768;  i += 256) a0p[i] = z;
    for (int i = tid; i < 1024; i += 256) a1p[i] = z;
    if (tid < 128) ((uint4*)sWoutF)[tid] = ((const uint4*)pw)[224 * 64 + tid];
    if (tid < 128) xsrc[0][tid] = src[(long)(rowg0 + (tid >> 2)) * 256 + (tid & 3)];
  }
  const float4 wv = *(const float4*)&W_in[mm * 4];
  const float  bin = b_in[mm];

  bf16x8 B0[3][4], B1[4][4];
  float bias0[4], bias1[4];
  float c0[8] = {0,0,0,0,0,0,0,0}, c1[8] = {0,0,0,0,0,0,0,0};
  load_frags(pw, 0, 48, w, lane, B0, B1);
#pragma unroll
  for (int g = 0; g < 4; g++){
    int n = 64*g + j;
    float s = (g == 2) ? -2.88539008f : -1.44269504f;   // match weight pre-scale
    bias0[g] = eb0[n] * s; bias1[g] = eb1[n] * s;
  }
  bar_lds();

  unsigned short h0r[8], h1r[8];
  const int xoff = (xr | ((mm >> 3) << 4)) * 8 + (mm & 7);   // A-layout slot for k=mm

  // ================= encoder: 1 barrier/step (cell1 skewed by 1) =================
  for (int t = 0; t < 64; t++){
    int cur = t & 1, nxt = cur ^ 1;
    float xv;
    if (tid < 128)
      xv = src[(long)(rowg0 + (tid >> 2)) * 256 + ((t == 63 ? 63 : t + 1) << 2) + (tid & 3)];
    { // x-projection for rows xr, xr+16
      float4 x0 = *(const float4*)&xsrc[cur][xr * 4];
      float4 x1 = *(const float4*)&xsrc[cur][(xr + 16) * 4];
      float m0 = bin + x0.x*wv.x + x0.y*wv.y + x0.z*wv.z + x0.w*wv.w;
      float m1 = bin + x1.x*wv.x + x1.y*wv.y + x1.z*wv.z + x1.w*wv.w;
      A0[cur][0][xoff] = f2bf(m0);
      A0[cur][1][xoff] = f2bf(m1);
    }
    if (tid < 128) xsrc[nxt][tid] = xv;
    bar_lds();
    // cell0(t)
    cell_compute<3, 1536>(&A0[cur][0][0], B0, bias0, c0, h0r, lane);
#pragma unroll
    for (int rt = 0; rt < 2; rt++){
      write_h(&A0[nxt][rt][0], 32 + j, quad, h0r + rt * 4);   // recurrent h0
      write_h(&A1[cur][rt][0],      j, quad, h0r + rt * 4);   // feed layer 1
    }
    // cell1(t-1) — inputs written during iter t-1, visible since barrier above
    if (t > 0){
      cell_compute<4, 2048>(&A1[nxt][0][0], B1, bias1, c1, h1r, lane);
#pragma unroll
      for (int rt = 0; rt < 2; rt++)
        write_h(&A1[cur][rt][0], 64 + j, quad, h1r + rt * 4); // recurrent h1
    }
  }
  bar_lds();
  // flush cell1(63): reads A1[1], writes recurrent into A1[0] for decoder t=0
  cell_compute<4, 2048>(&A1[1][0][0], B1, bias1, c1, h1r, lane);
#pragma unroll
  for (int rt = 0; rt < 2; rt++)
    write_h(&A1[0][rt][0], 64 + j, quad, h1r + rt * 4);
  // NOTE: A0[0] k=32..95 holds h0_enc(63) = decoder L0's initial hidden (matches ref init)

  // ================= decoder (3 barriers/step) =================
  load_frags(pw, 112, 160, w, lane, B0, B1);
#pragma unroll
  for (int g = 0; g < 4; g++){
    int n = 64*g + j;
    float s = (g == 2) ? -2.88539008f : -1.44269504f;
    bias0[g] = db0[n] * s; bias1[g] = db1[n] * s;
  }
  const float bo = (w < 2 && l16 < 4) ? bout[l16] : 0.0f;
  { // m(0) = trg(:,0) @ W_in^T + b_in  ->  A0[0] m-slots
    float4 x0 = *(const float4*)&trg[(long)(rowg0 + xr) * 256];
    float4 x1 = *(const float4*)&trg[(long)(rowg0 + xr + 16) * 256];
    float m0 = bin + x0.x*wv.x + x0.y*wv.y + x0.z*wv.z + x0.w*wv.w;
    float m1 = bin + x1.x*wv.x + x1.y*wv.y + x1.z*wv.z + x1.w*wv.w;
    A0[0][0][xoff] = f2bf(m0);
    A0[0][1][xoff] = f2bf(m1);
  }
  bar_lds();

  for (int t = 0; t < 64; t++){
    int cur = t & 1, nxt = cur ^ 1;
    float tpre[4] = {0.0f, 0.0f, 0.0f, 0.0f};
    if (w < 2 && l16 < 4){
#pragma unroll
      for (int e = 0; e < 4; e++)
        tpre[e] = trg[(long)(rowg0 + w * 16 + quad * 4 + e) * 256 + t * 4 + l16];
    }
    // cell0(t): reads A0[cur] (m from proj(t-1), h0(t-1) recurrent)
    cell_compute<3, 1536>(&A0[cur][0][0], B0, bias0, c0, h0r, lane);
#pragma unroll
    for (int rt = 0; rt < 2; rt++){
      write_h(&A0[nxt][rt][0], 32 + j, quad, h0r + rt * 4);   // recurrent h0 for t+1
      write_h(&A1[cur][rt][0],      j, quad, h0r + rt * 4);   // feed layer 1
    }
    bar_lds();                             // barB: h0 visible
    cell_compute<4, 2048>(&A1[cur][0][0], B1, bias1, c1, h1r, lane);
#pragma unroll
    for (int rt = 0; rt < 2; rt++)
      write_h(&A1[nxt][rt][0], 64 + j, quad, h1r + rt * 4);   // recurrent h1 for t+1
    bar_lds();                             // barC: h1(t) visible
    if (w < 2){                            // proj + in-register next-step m-proj
      const unsigned short* Ah = &A1[nxt][w][0];
      bf16x8 a2 = *(const bf16x8*)(Ah + (2 * 64 + lane) * 8);
      bf16x8 a3 = *(const bf16x8*)(Ah + (3 * 64 + lane) * 8);
      bf16x8 bw0 = *(const bf16x8*)(sWoutF + lane * 8);
      bf16x8 bw1 = *(const bf16x8*)(sWoutF + 512 + lane * 8);
      f32x4 po = {bo, bo, bo, bo};
      po = __builtin_amdgcn_mfma_f32_16x16x32_bf16(a2, bw0, po, 0, 0, 0);
      po = __builtin_amdgcn_mfma_f32_16x16x32_bf16(a3, bw1, po, 0, 0, 0);
      float v[4];
#pragma unroll
      for (int e = 0; e < 4; e++){
        float val = po[e] + tpre[e];       // feedback x component l16 (valid l16<4)
        if (l16 < 4)
          out[(long)(rowg0 + w * 16 + quad * 4 + e) * 256 + t * 4 + l16] = val;
        v[e] = val;
      }
      // m(t+1)[k=l16] for rows quad*4+e: gather the 4 x-components from lanes
      // quad*16+{0..3} (ds_bpermute, no barrier), dot with this lane's wv/bin.
      int qb = lane & 48;
      unsigned short* Ad = &A0[nxt][w][0];
#pragma unroll
      for (int e = 0; e < 4; e++){
        float cx = __shfl(v[e], qb + 0, 64);
        float cy = __shfl(v[e], qb + 1, 64);
        float cz = __shfl(v[e], qb + 2, 64);
        float cw = __shfl(v[e], qb + 3, 64);
        float mval = bin + cx*wv.x + cy*wv.y + cz*wv.z + cw*wv.w;
        Ad[((quad * 4 + e) | ((l16 >> 3) << 4)) * 8 + (l16 & 7)] = f2bf(mval);
      }
    }
    bar_lds();                             // barNext: A0[nxt] (m + h0) ready
  }
}

extern "C" void kernel_launch(void* const* d_in, const int* in_sizes, int n_in,
                              void* d_out, int out_size, void* d_ws, size_t ws_size,
                              hipStream_t stream){
  (void)n_in; (void)out_size; (void)ws_size;
  const float* src   = (const float*)d_in[0];
  const float* trg   = (const float*)d_in[1];
  const float* W_in  = (const float*)d_in[2];
  const float* b_in  = (const float*)d_in[3];
  const float* eWih0 = (const float*)d_in[4];
  const float* eWhh0 = (const float*)d_in[5];
  const float* eb0   = (const float*)d_in[6];
  const float* eWih1 = (const float*)d_in[7];
  const float* eWhh1 = (const float*)d_in[8];
  const float* eb1   = (const float*)d_in[9];
  const float* dWih0 = (const float*)d_in[10];
  const float* dWhh0 = (const float*)d_in[11];
  const float* db0   = (const float*)d_in[12];
  const float* dWih1 = (const float*)d_in[13];
  const float* dWhh1 = (const float*)d_in[14];
  const float* db1   = (const float*)d_in[15];
  const float* Wout  = (const float*)d_in[16];
  const float* bout  = (const float*)d_in[17];
  unsigned short* pw = (unsigned short*)d_ws;          // needs 231,424 bytes

  pack_weights<<<57, 256, 0, stream>>>(eWih0, eWhh0, eWih1, eWhh1,
                                       dWih0, dWhh0, dWih1, dWhh1, Wout, pw);

  int B    = in_sizes[0] / 256;                        // S*I = 256
  int nblk = B / 32;
  lstm_main<<<nblk, 256, 0, stream>>>(src, trg, W_in, b_in, eb0, eb1, db0, db1,
                                      bout, pw, (float*)d_out);
}

// Round 9
// 440.597 us; speedup vs baseline: 1.0268x; 1.0268x over previous
//
#include <hip/hip_runtime.h>

typedef __bf16 bf16x8 __attribute__((ext_vector_type(8)));
typedef float  f32x4  __attribute__((ext_vector_type(4)));

__device__ __forceinline__ unsigned short f2bf(float x){
  return __builtin_bit_cast(unsigned short, (__bf16)x);   // HW v_cvt on gfx950, RNE
}

// LDS-only barrier: all our inter-wave hazards are LDS ping-pong buffers, so
// wait lgkmcnt(0) only — do NOT drain vmcnt (keeps trg prefetch + out[] store
// acks in flight across the barrier, unlike __syncthreads()).
__device__ __forceinline__ void bar_lds(){
  asm volatile("s_waitcnt lgkmcnt(0)" ::: "memory");
  __builtin_amdgcn_s_barrier();
  asm volatile("" ::: "memory");
}

// ---------------------------------------------------------------------------
// Weight pack: MFMA B-fragment order (bf16), lane holds B[k=kt*32+(lane>>4)*8+jj][n=lane&15].
// Gate weights PRE-SCALED by -log2(e) (i,f,o) or -2*log2(e) (g) so the MFMA
// accumulator is directly the exp2() argument.
// Frag sections: [0,48) encL0 (ntile*3+kt, K: x 0..16|pad|h 32..96)
//                [48,112) encL1 (ntile*4+kt, K: h0 0..64|h1 64..128)
//                [112,160) decL0, [160,224) decL1, [224,226) W_out (N=4 padded to 16, K=64)
// NOTE: the frag byte pattern (lane&15 picks the 16-dim, (lane>>4)*8+jj the
// K-dim) serves as BOTH a B-frag of W and an A-frag of W — sWoutF is reused
// as the A-operand in the decoder's transposed projection.
// ---------------------------------------------------------------------------
__global__ void pack_weights(const float* __restrict__ eWih0, const float* __restrict__ eWhh0,
                             const float* __restrict__ eWih1, const float* __restrict__ eWhh1,
                             const float* __restrict__ dWih0, const float* __restrict__ dWhh0,
                             const float* __restrict__ dWih1, const float* __restrict__ dWhh1,
                             const float* __restrict__ Wout,
                             unsigned short* __restrict__ out){
  int t = blockIdx.x * 256 + threadIdx.x;
  if (t >= 226 * 64) return;
  int lane = t & 63;
  int f    = t >> 6;
  unsigned short vals[8];
  if (f >= 224){                                       // W_out frags (NOT scaled)
    int kt = f - 224, n = lane & 15;
#pragma unroll
    for (int jj = 0; jj < 8; jj++){
      int k = kt * 32 + (lane >> 4) * 8 + jj;
      vals[jj] = (n < 4) ? f2bf(Wout[n * 64 + k]) : (unsigned short)0;
    }
  } else {
    const float *Wih, *Whh; int kx, ntile, kt;
    if (f < 48)       { Wih=eWih0; Whh=eWhh0; kx=16; ntile=f/3;        kt=f%3; }
    else if (f < 112) { Wih=eWih1; Whh=eWhh1; kx=64; ntile=(f-48)/4;   kt=(f-48)%4; }
    else if (f < 160) { Wih=dWih0; Whh=dWhh0; kx=16; ntile=(f-112)/3;  kt=(f-112)%3; }
    else              { Wih=dWih1; Whh=dWhh1; kx=64; ntile=(f-160)/4;  kt=(f-160)%4; }
    int n    = ntile * 16 + (lane & 15);
    int hoff = (kx == 16) ? 32 : 64;
    // gate index = n/64 = ntile/4; gates i,f,o get -log2(e), gate g gets -2*log2(e)
    float scale = ((ntile >> 2) == 2) ? -2.88539008f : -1.44269504f;
#pragma unroll
    for (int jj = 0; jj < 8; jj++){
      int k = kt * 32 + (lane >> 4) * 8 + jj;
      float v;
      if (k < kx)        v = Wih[n * kx + k];
      else if (k < hoff) v = 0.0f;
      else               v = Whh[n * 64 + (k - hoff)];
      vals[jj] = f2bf(v * scale);
    }
  }
  uint4 o;
  o.x = (unsigned)vals[0] | ((unsigned)vals[1] << 16);
  o.y = (unsigned)vals[2] | ((unsigned)vals[3] << 16);
  o.z = (unsigned)vals[4] | ((unsigned)vals[5] << 16);
  o.w = (unsigned)vals[6] | ((unsigned)vals[7] << 16);
  ((uint4*)out)[f * 64 + lane] = o;
}

// A-layout (per 16-row subtile): elem(m,k) at ((k>>5)*64 + (m | (((k>>3)&3)<<4)))*8 + (k&7)
// Self-transpose property: a bf16x8 read at (kt*64+lane)*8 is simultaneously
// the A-frag of the tile AND the B-frag of the tile's transpose.
__device__ __forceinline__ void write_h(unsigned short* buf, int k, int quad,
                                        const unsigned short* h){
  unsigned short* p = buf + (((k >> 5) * 64) + quad * 4 + (((k >> 3) & 3) << 4)) * 8 + (k & 7);
#pragma unroll
  for (int e = 0; e < 4; e++) p[e * 8] = h[e];
}

__device__ __forceinline__ void load_frags(const unsigned short* __restrict__ pw,
                                           int base0, int base1, int w, int lane,
                                           bf16x8 (&B0)[3][4], bf16x8 (&B1)[4][4]){
#pragma unroll
  for (int g = 0; g < 4; g++){
    int nt = 4 * g + w;
#pragma unroll
    for (int kt = 0; kt < 3; kt++)
      B0[kt][g] = *(const bf16x8*)(pw + (((long)(base0 + nt * 3 + kt)) * 64 + lane) * 8);
#pragma unroll
    for (int kt = 0; kt < 4; kt++)
      B1[kt][g] = *(const bf16x8*)(pw + (((long)(base1 + nt * 4 + kt)) * 64 + lane) * 8);
  }
}

// One LSTM cell step for 32 rows (2 row-subtiles of 16, interleaved: 8 indep
// MFMA chains), this wave's 16 j's. acc arrives exp2-ready (pre-scaled weights).
// Single-rcp c-update (common denominator):
//   c2 = [c*(1+ei)(1+eg) + K(1-eg)(1+ef)] / [(1+ef)(1+ei)(1+eg)],  K = 2*log2(e)
//   sig(o)*tanh(c) = (ec-1)/((1+eo)(1+ec)),  ec = exp2(c2) = e^{2c}
template<int KT, int SZ>
__device__ __forceinline__ void cell_compute(const unsigned short* __restrict__ A,
                                             const bf16x8 (&B)[KT][4],
                                             const float (&bias)[4],
                                             float (&c)[8],
                                             unsigned short (&hout)[8],
                                             int lane){
  f32x4 acc[4][2];
#pragma unroll
  for (int g = 0; g < 4; g++){
    f32x4 b = {bias[g], bias[g], bias[g], bias[g]};
    acc[g][0] = b; acc[g][1] = b;
  }
#pragma unroll
  for (int kt = 0; kt < KT; kt++){
    bf16x8 a0 = *(const bf16x8*)(A +      (kt * 64 + lane) * 8);
    bf16x8 a1 = *(const bf16x8*)(A + SZ + (kt * 64 + lane) * 8);
#pragma unroll
    for (int g = 0; g < 4; g++){
      acc[g][0] = __builtin_amdgcn_mfma_f32_16x16x32_bf16(a0, B[kt][g], acc[g][0], 0, 0, 0);
      acc[g][1] = __builtin_amdgcn_mfma_f32_16x16x32_bf16(a1, B[kt][g], acc[g][1], 0, 0, 0);
    }
  }
#pragma unroll
  for (int rt = 0; rt < 2; rt++){
#pragma unroll
    for (int e = 0; e < 4; e++){
      int idx = rt * 4 + e;
      float ei = __builtin_amdgcn_exp2f(acc[0][rt][e]);   // e^{-i}
      float ef = __builtin_amdgcn_exp2f(acc[1][rt][e]);   // e^{-f}
      float eg = __builtin_amdgcn_exp2f(acc[2][rt][e]);   // e^{-2g}
      float eo = __builtin_amdgcn_exp2f(acc[3][rt][e]);   // e^{-o}
      float pf   = 1.0f + ef;
      float pig  = (1.0f + ei) * (1.0f + eg);
      float rden = __builtin_amdgcn_rcpf(pf * pig);
      float num  = fmaf(fmaf(-2.88539008f, eg, 2.88539008f), pf, c[idx] * pig);
      float c2   = num * rden;
      c[idx] = c2;
      float ec  = __builtin_amdgcn_exp2f(c2);             // e^{2c}
      float rot = __builtin_amdgcn_rcpf((1.0f + eo) * (1.0f + ec));
      hout[idx] = f2bf((ec - 1.0f) * rot);                // sig(o)*tanh(c)
    }
  }
}

// ---------------------------------------------------------------------------
// Main: one block = 32 batch rows. Encoder: 1 barrier/step (layer-skewed).
// Decoder: 3 barriers/step — projC computes pred^T via mfma(Wout, h1-bytes)
// (self-transposing LDS read), adds trg (float4), stores out (float4), then
// chains mfma(W_in, x^T) to produce next-step m already transposed into
// A-layout, written with one ds_write_b64. No shfl, no xfb round-trip.
// ---------------------------------------------------------------------------
__global__ __launch_bounds__(256, 2)
void lstm_main(const float* __restrict__ src, const float* __restrict__ trg,
               const float* __restrict__ W_in, const float* __restrict__ b_in,
               const float* __restrict__ eb0, const float* __restrict__ eb1,
               const float* __restrict__ db0, const float* __restrict__ db1,
               const float* __restrict__ bout,
               const unsigned short* __restrict__ pw,
               float* __restrict__ out){
  __shared__ __align__(16) unsigned short A0[2][2][1536];   // ping-pong, 2 row-subtiles, K=96
  __shared__ __align__(16) unsigned short A1[2][2][2048];   // K=128
  __shared__ __align__(16) float xsrc[2][128];              // encoder x ping-pong (32 rows x 4)
  __shared__ __align__(16) unsigned short sWoutF[1024];     // W_out frags (A- and B-usable)
  __shared__ __align__(16) unsigned short sWinF[512];       // W_in A-frag (K=4 padded to 32)

  const int tid  = threadIdx.x;
  const int lane = tid & 63;
  const int w    = tid >> 6;
  const int quad = lane >> 4;
  const int l16  = lane & 15;
  const int j    = 16 * w + l16;
  const int rowg0 = blockIdx.x * 32;
  const int mm   = tid & 15;                  // x-proj: this thread's m-unit
  const int xr   = tid >> 4;                  // x-proj: rows xr and xr+16

  // ---- staging ----
  {
    uint4 z; z.x = z.y = z.z = z.w = 0u;
    uint4* a0p = (uint4*)A0;                  // 768 uint4
    uint4* a1p = (uint4*)A1;                  // 1024 uint4
    for (int i = tid; i < 768;  i += 256) a0p[i] = z;
    for (int i = tid; i < 1024; i += 256) a1p[i] = z;
    if (tid < 128) ((uint4*)sWoutF)[tid] = ((const uint4*)pw)[224 * 64 + tid];
    if (tid < 64){                            // W_in A-frag: lane<16, jj<4 = W_in[l][jj]
      unsigned short v[8] = {0,0,0,0,0,0,0,0};
      if (tid < 16){
#pragma unroll
        for (int jj = 0; jj < 4; jj++) v[jj] = f2bf(W_in[tid * 4 + jj]);
      }
      uint4 o;
      o.x = (unsigned)v[0] | ((unsigned)v[1] << 16);
      o.y = (unsigned)v[2] | ((unsigned)v[3] << 16);
      o.z = o.w = 0u;
      ((uint4*)sWinF)[tid] = o;
    }
    if (tid < 128) xsrc[0][tid] = src[(long)(rowg0 + (tid >> 2)) * 256 + (tid & 3)];
  }
  const float4 wv = *(const float4*)&W_in[mm * 4];
  const float  bin = b_in[mm];

  bf16x8 B0[3][4], B1[4][4];
  float bias0[4], bias1[4];
  float c0[8] = {0,0,0,0,0,0,0,0}, c1[8] = {0,0,0,0,0,0,0,0};
  load_frags(pw, 0, 48, w, lane, B0, B1);
#pragma unroll
  for (int g = 0; g < 4; g++){
    int n = 64*g + j;
    float s = (g == 2) ? -2.88539008f : -1.44269504f;   // match weight pre-scale
    bias0[g] = eb0[n] * s; bias1[g] = eb1[n] * s;
  }
  bar_lds();

  unsigned short h0r[8], h1r[8];
  const int xoff = (xr | ((mm >> 3) << 4)) * 8 + (mm & 7);   // A-layout slot for k=mm

  // ================= encoder: 1 barrier/step (cell1 skewed by 1) =================
  for (int t = 0; t < 64; t++){
    int cur = t & 1, nxt = cur ^ 1;
    float xv;
    if (tid < 128)
      xv = src[(long)(rowg0 + (tid >> 2)) * 256 + ((t == 63 ? 63 : t + 1) << 2) + (tid & 3)];
    { // x-projection for rows xr, xr+16
      float4 x0 = *(const float4*)&xsrc[cur][xr * 4];
      float4 x1 = *(const float4*)&xsrc[cur][(xr + 16) * 4];
      float m0 = bin + x0.x*wv.x + x0.y*wv.y + x0.z*wv.z + x0.w*wv.w;
      float m1 = bin + x1.x*wv.x + x1.y*wv.y + x1.z*wv.z + x1.w*wv.w;
      A0[cur][0][xoff] = f2bf(m0);
      A0[cur][1][xoff] = f2bf(m1);
    }
    if (tid < 128) xsrc[nxt][tid] = xv;
    bar_lds();
    // cell0(t)
    cell_compute<3, 1536>(&A0[cur][0][0], B0, bias0, c0, h0r, lane);
#pragma unroll
    for (int rt = 0; rt < 2; rt++){
      write_h(&A0[nxt][rt][0], 32 + j, quad, h0r + rt * 4);   // recurrent h0
      write_h(&A1[cur][rt][0],      j, quad, h0r + rt * 4);   // feed layer 1
    }
    // cell1(t-1) — inputs written during iter t-1, visible since barrier above
    if (t > 0){
      cell_compute<4, 2048>(&A1[nxt][0][0], B1, bias1, c1, h1r, lane);
#pragma unroll
      for (int rt = 0; rt < 2; rt++)
        write_h(&A1[cur][rt][0], 64 + j, quad, h1r + rt * 4); // recurrent h1
    }
  }
  bar_lds();
  // flush cell1(63): reads A1[1], writes recurrent into A1[0] for decoder t=0
  cell_compute<4, 2048>(&A1[1][0][0], B1, bias1, c1, h1r, lane);
#pragma unroll
  for (int rt = 0; rt < 2; rt++)
    write_h(&A1[0][rt][0], 64 + j, quad, h1r + rt * 4);
  // NOTE: A0[0] k=32..95 holds h0_enc(63) = decoder L0's initial hidden (matches ref init)

  // ================= decoder (3 barriers/step) =================
  load_frags(pw, 112, 160, w, lane, B0, B1);
#pragma unroll
  for (int g = 0; g < 4; g++){
    int n = 64*g + j;
    float s = (g == 2) ? -2.88539008f : -1.44269504f;
    bias0[g] = db0[n] * s; bias1[g] = db1[n] * s;
  }
  // per-lane constants for the transposed projection chain
  const float4 bq   = *(const float4*)&b_in[quad * 4];      // b_in[quad*4+e] (C-init of m^T)
  f32x4 boT = {0.0f, 0.0f, 0.0f, 0.0f};
  if (quad == 0){
    float4 b4 = *(const float4*)bout;
    boT[0] = b4.x; boT[1] = b4.y; boT[2] = b4.z; boT[3] = b4.w;
  }
  { // m(0) = trg(:,0) @ W_in^T + b_in  ->  A0[0] m-slots
    float4 x0 = *(const float4*)&trg[(long)(rowg0 + xr) * 256];
    float4 x1 = *(const float4*)&trg[(long)(rowg0 + xr + 16) * 256];
    float m0 = bin + x0.x*wv.x + x0.y*wv.y + x0.z*wv.z + x0.w*wv.w;
    float m1 = bin + x1.x*wv.x + x1.y*wv.y + x1.z*wv.z + x1.w*wv.w;
    A0[0][0][xoff] = f2bf(m0);
    A0[0][1][xoff] = f2bf(m1);
  }
  bar_lds();

  for (int t = 0; t < 64; t++){
    int cur = t & 1, nxt = cur ^ 1;
    float4 tpreT = {0.0f, 0.0f, 0.0f, 0.0f};
    if (w < 2 && quad == 0)                  // row = w*16+l16, comps t*4..t*4+3 (float4)
      tpreT = *(const float4*)&trg[(long)(rowg0 + w * 16 + l16) * 256 + t * 4];
    // cell0(t): reads A0[cur] (m from projC(t-1), h0(t-1) recurrent)
    cell_compute<3, 1536>(&A0[cur][0][0], B0, bias0, c0, h0r, lane);
#pragma unroll
    for (int rt = 0; rt < 2; rt++){
      write_h(&A0[nxt][rt][0], 32 + j, quad, h0r + rt * 4);   // recurrent h0 for t+1
      write_h(&A1[cur][rt][0],      j, quad, h0r + rt * 4);   // feed layer 1
    }
    bar_lds();                             // barB: h0 visible
    cell_compute<4, 2048>(&A1[cur][0][0], B1, bias1, c1, h1r, lane);
#pragma unroll
    for (int rt = 0; rt < 2; rt++)
      write_h(&A1[nxt][rt][0], 64 + j, quad, h1r + rt * 4);   // recurrent h1 for t+1
    bar_lds();                             // barC: h1(t) visible
    if (w < 2){                            // projC (wave w = row-subtile w)
      const unsigned short* Ah = &A1[nxt][w][0];
      // self-transposing reads: these bytes are the B-frag of h1^T
      bf16x8 hb0 = *(const bf16x8*)(Ah + (2 * 64 + lane) * 8);
      bf16x8 hb1 = *(const bf16x8*)(Ah + (3 * 64 + lane) * 8);
      bf16x8 wa0 = *(const bf16x8*)(sWoutF + lane * 8);       // Wout as A-frag
      bf16x8 wa1 = *(const bf16x8*)(sWoutF + 512 + lane * 8);
      f32x4 po = boT;                                         // pred^T = Wout @ h1^T
      po = __builtin_amdgcn_mfma_f32_16x16x32_bf16(wa0, hb0, po, 0, 0, 0);
      po = __builtin_amdgcn_mfma_f32_16x16x32_bf16(wa1, hb1, po, 0, 0, 0);
      // quad0 lane l16 holds x[row=l16][e] = po[e] + trg
      unsigned int xp0 = 0u, xp1 = 0u;
      if (quad == 0){
        float4 xv;
        xv.x = po[0] + tpreT.x;  xv.y = po[1] + tpreT.y;
        xv.z = po[2] + tpreT.z;  xv.w = po[3] + tpreT.w;
        *(float4*)&out[(long)(rowg0 + w * 16 + l16) * 256 + t * 4] = xv;
        xp0 = (unsigned)f2bf(xv.x) | ((unsigned)f2bf(xv.y) << 16);
        xp1 = (unsigned)f2bf(xv.z) | ((unsigned)f2bf(xv.w) << 16);
      }
      uint4 xb_u; xb_u.x = xp0; xb_u.y = xp1; xb_u.z = 0u; xb_u.w = 0u;
      bf16x8 xb = __builtin_bit_cast(bf16x8, xb_u);           // B-frag of x^T (K=4 pad 32)
      bf16x8 wi = *(const bf16x8*)(sWinF + lane * 8);         // W_in as A-frag
      f32x4 pm = {bq.x, bq.y, bq.z, bq.w};                    // m^T = W_in @ x^T + b_in
      pm = __builtin_amdgcn_mfma_f32_16x16x32_bf16(wi, xb, pm, 0, 0, 0);
      // lane holds m[row=l16][mm=quad*4+e]; 4 consecutive halfwords in A-layout
      unsigned int mp0 = (unsigned)f2bf(pm[0]) | ((unsigned)f2bf(pm[1]) << 16);
      unsigned int mp1 = (unsigned)f2bf(pm[2]) | ((unsigned)f2bf(pm[3]) << 16);
      uint2 mw; mw.x = mp0; mw.y = mp1;
      *(uint2*)&A0[nxt][w][(l16 | ((quad >> 1) << 4)) * 8 + (quad & 1) * 4] = mw;
    }
    bar_lds();                             // barNext: A0[nxt] (m + h0) ready
  }
}

extern "C" void kernel_launch(void* const* d_in, const int* in_sizes, int n_in,
                              void* d_out, int out_size, void* d_ws, size_t ws_size,
                              hipStream_t stream){
  (void)n_in; (void)out_size; (void)ws_size;
  const float* src   = (const float*)d_in[0];
  const float* trg   = (const float*)d_in[1];
  const float* W_in  = (const float*)d_in[2];
  const float* b_in  = (const float*)d_in[3];
  const float* eWih0 = (const float*)d_in[4];
  const float* eWhh0 = (const float*)d_in[5];
  const float* eb0   = (const float*)d_in[6];
  const float* eWih1 = (const float*)d_in[7];
  const float* eWhh1 = (const float*)d_in[8];
  const float* eb1   = (const float*)d_in[9];
  const float* dWih0 = (const float*)d_in[10];
  const float* dWhh0 = (const float*)d_in[11];
  const float* db0   = (const float*)d_in[12];
  const float* dWih1 = (const float*)d_in[13];
  const float* dWhh1 = (const float*)d_in[14];
  const float* db1   = (const float*)d_in[15];
  const float* Wout  = (const float*)d_in[16];
  const float* bout  = (const float*)d_in[17];
  unsigned short* pw = (unsigned short*)d_ws;          // needs 231,424 bytes

  pack_weights<<<57, 256, 0, stream>>>(eWih0, eWhh0, eWih1, eWhh1,
                                       dWih0, dWhh0, dWih1, dWhh1, Wout, pw);

  int B    = in_sizes[0] / 256;                        // S*I = 256
  int nblk = B / 32;
  lstm_main<<<nblk, 256, 0, stream>>>(src, trg, W_in, b_in, eb0, eb1, db0, db1,
                                      bout, pw, (float*)d_out);
}

// Round 10
// 434.707 us; speedup vs baseline: 1.0408x; 1.0135x over previous
//
#include <hip/hip_runtime.h>

typedef __bf16 bf16x8 __attribute__((ext_vector_type(8)));
typedef float  f32x4  __attribute__((ext_vector_type(4)));

__device__ __forceinline__ unsigned short f2bf(float x){
  return __builtin_bit_cast(unsigned short, (__bf16)x);   // HW v_cvt on gfx950, RNE
}

// LDS-only barrier: all our inter-wave hazards are LDS ping-pong buffers, so
// wait lgkmcnt(0) only — do NOT drain vmcnt (keeps trg prefetch + out[] store
// acks in flight across the barrier, unlike __syncthreads()).
__device__ __forceinline__ void bar_lds(){
  asm volatile("s_waitcnt lgkmcnt(0)" ::: "memory");
  __builtin_amdgcn_s_barrier();
  asm volatile("" ::: "memory");
}

// ---------------------------------------------------------------------------
// Weight pack: MFMA B-fragment order (bf16), lane holds B[k=kt*32+(lane>>4)*8+jj][n=lane&15].
// Gate weights PRE-SCALED by -log2(e) (i,f,o) or -2*log2(e) (g) so the MFMA
// accumulator is directly the exp2() argument.
// Frag sections: [0,48) encL0 (ntile*3+kt, K: x 0..16|pad|h 32..96)
//                [48,112) encL1 (ntile*4+kt, K: h0 0..64|h1 64..128)
//                [112,160) decL0, [160,224) decL1, [224,226) W_out (N=4 padded to 16, K=64)
// NOTE: the frag byte pattern (lane&15 picks the 16-dim, (lane>>4)*8+jj the
// K-dim) serves as BOTH a B-frag of W and an A-frag of W — sWoutF is reused
// as the A-operand in the decoder's transposed projection.
// ---------------------------------------------------------------------------
__global__ void pack_weights(const float* __restrict__ eWih0, const float* __restrict__ eWhh0,
                             const float* __restrict__ eWih1, const float* __restrict__ eWhh1,
                             const float* __restrict__ dWih0, const float* __restrict__ dWhh0,
                             const float* __restrict__ dWih1, const float* __restrict__ dWhh1,
                             const float* __restrict__ Wout,
                             unsigned short* __restrict__ out){
  int t = blockIdx.x * 256 + threadIdx.x;
  if (t >= 226 * 64) return;
  int lane = t & 63;
  int f    = t >> 6;
  unsigned short vals[8];
  if (f >= 224){                                       // W_out frags (NOT scaled)
    int kt = f - 224, n = lane & 15;
#pragma unroll
    for (int jj = 0; jj < 8; jj++){
      int k = kt * 32 + (lane >> 4) * 8 + jj;
      vals[jj] = (n < 4) ? f2bf(Wout[n * 64 + k]) : (unsigned short)0;
    }
  } else {
    const float *Wih, *Whh; int kx, ntile, kt;
    if (f < 48)       { Wih=eWih0; Whh=eWhh0; kx=16; ntile=f/3;        kt=f%3; }
    else if (f < 112) { Wih=eWih1; Whh=eWhh1; kx=64; ntile=(f-48)/4;   kt=(f-48)%4; }
    else if (f < 160) { Wih=dWih0; Whh=dWhh0; kx=16; ntile=(f-112)/3;  kt=(f-112)%3; }
    else              { Wih=dWih1; Whh=dWhh1; kx=64; ntile=(f-160)/4;  kt=(f-160)%4; }
    int n    = ntile * 16 + (lane & 15);
    int hoff = (kx == 16) ? 32 : 64;
    // gate index = n/64 = ntile/4; gates i,f,o get -log2(e), gate g gets -2*log2(e)
    float scale = ((ntile >> 2) == 2) ? -2.88539008f : -1.44269504f;
#pragma unroll
    for (int jj = 0; jj < 8; jj++){
      int k = kt * 32 + (lane >> 4) * 8 + jj;
      float v;
      if (k < kx)        v = Wih[n * kx + k];
      else if (k < hoff) v = 0.0f;
      else               v = Whh[n * 64 + (k - hoff)];
      vals[jj] = f2bf(v * scale);
    }
  }
  uint4 o;
  o.x = (unsigned)vals[0] | ((unsigned)vals[1] << 16);
  o.y = (unsigned)vals[2] | ((unsigned)vals[3] << 16);
  o.z = (unsigned)vals[4] | ((unsigned)vals[5] << 16);
  o.w = (unsigned)vals[6] | ((unsigned)vals[7] << 16);
  ((uint4*)out)[f * 64 + lane] = o;
}

// A-layout (per 16-row subtile): elem(m,k) at ((k>>5)*64 + (m | (((k>>3)&3)<<4)))*8 + (k&7)
// Self-transpose property: a bf16x8 read at (kt*64+lane)*8 is simultaneously
// the A-frag of the tile AND the B-frag of the tile's transpose.
__device__ __forceinline__ void write_h(unsigned short* buf, int k, int quad,
                                        const unsigned short* h){
  unsigned short* p = buf + (((k >> 5) * 64) + quad * 4 + (((k >> 3) & 3) << 4)) * 8 + (k & 7);
#pragma unroll
  for (int e = 0; e < 4; e++) p[e * 8] = h[e];
}

__device__ __forceinline__ void load_frags(const unsigned short* __restrict__ pw,
                                           int base0, int base1, int w, int lane,
                                           bf16x8 (&B0)[3][4], bf16x8 (&B1)[4][4]){
#pragma unroll
  for (int g = 0; g < 4; g++){
    int nt = 4 * g + w;
#pragma unroll
    for (int kt = 0; kt < 3; kt++)
      B0[kt][g] = *(const bf16x8*)(pw + (((long)(base0 + nt * 3 + kt)) * 64 + lane) * 8);
#pragma unroll
    for (int kt = 0; kt < 4; kt++)
      B1[kt][g] = *(const bf16x8*)(pw + (((long)(base1 + nt * 4 + kt)) * 64 + lane) * 8);
  }
}

// Shared activation epilogue: acc (exp2-ready) -> c update + h (bf16).
// Single-rcp c-update (common denominator):
//   c2 = [c*(1+ei)(1+eg) + K(1-eg)(1+ef)] / [(1+ef)(1+ei)(1+eg)],  K = 2*log2(e)
//   sig(o)*tanh(c) = (ec-1)/((1+eo)(1+ec)),  ec = exp2(c2) = e^{2c}
__device__ __forceinline__ void cell_act(f32x4 (&acc)[4][2], float (&c)[8],
                                         unsigned short (&hout)[8]){
#pragma unroll
  for (int rt = 0; rt < 2; rt++){
#pragma unroll
    for (int e = 0; e < 4; e++){
      int idx = rt * 4 + e;
      float ei = __builtin_amdgcn_exp2f(acc[0][rt][e]);   // e^{-i}
      float ef = __builtin_amdgcn_exp2f(acc[1][rt][e]);   // e^{-f}
      float eg = __builtin_amdgcn_exp2f(acc[2][rt][e]);   // e^{-2g}
      float eo = __builtin_amdgcn_exp2f(acc[3][rt][e]);   // e^{-o}
      float pf   = 1.0f + ef;
      float pig  = (1.0f + ei) * (1.0f + eg);
      float rden = __builtin_amdgcn_rcpf(pf * pig);
      float num  = fmaf(fmaf(-2.88539008f, eg, 2.88539008f), pf, c[idx] * pig);
      float c2   = num * rden;
      c[idx] = c2;
      float ec  = __builtin_amdgcn_exp2f(c2);             // e^{2c}
      float rot = __builtin_amdgcn_rcpf((1.0f + eo) * (1.0f + ec));
      hout[idx] = f2bf((ec - 1.0f) * rot);                // sig(o)*tanh(c)
    }
  }
}

// Full cell step for 32 rows (2 row-subtiles of 16, interleaved: 8 indep chains).
template<int KT, int SZ>
__device__ __forceinline__ void cell_compute(const unsigned short* __restrict__ A,
                                             const bf16x8 (&B)[KT][4],
                                             const float (&bias)[4],
                                             float (&c)[8],
                                             unsigned short (&hout)[8],
                                             int lane){
  f32x4 acc[4][2];
#pragma unroll
  for (int g = 0; g < 4; g++){
    f32x4 b = {bias[g], bias[g], bias[g], bias[g]};
    acc[g][0] = b; acc[g][1] = b;
  }
#pragma unroll
  for (int kt = 0; kt < KT; kt++){
    bf16x8 a0 = *(const bf16x8*)(A +      (kt * 64 + lane) * 8);
    bf16x8 a1 = *(const bf16x8*)(A + SZ + (kt * 64 + lane) * 8);
#pragma unroll
    for (int g = 0; g < 4; g++){
      acc[g][0] = __builtin_amdgcn_mfma_f32_16x16x32_bf16(a0, B[kt][g], acc[g][0], 0, 0, 0);
      acc[g][1] = __builtin_amdgcn_mfma_f32_16x16x32_bf16(a1, B[kt][g], acc[g][1], 0, 0, 0);
    }
  }
  cell_act(acc, c, hout);
}

// Decoder cell0 split across the barrier: START issues the h0 K-tiles (kt=1,2)
// — legal in the projC window since those A0-slots were written before barB —
// FINISH adds the m K-tile (kt=0, written by projC) and runs the activation.
__device__ __forceinline__ void cell0_start(const unsigned short* __restrict__ A,
                                            const bf16x8 (&B)[3][4],
                                            const float (&bias)[4],
                                            f32x4 (&acc)[4][2],
                                            int lane){
#pragma unroll
  for (int g = 0; g < 4; g++){
    f32x4 b = {bias[g], bias[g], bias[g], bias[g]};
    acc[g][0] = b; acc[g][1] = b;
  }
#pragma unroll
  for (int kt = 1; kt < 3; kt++){
    bf16x8 a0 = *(const bf16x8*)(A +        (kt * 64 + lane) * 8);
    bf16x8 a1 = *(const bf16x8*)(A + 1536 + (kt * 64 + lane) * 8);
#pragma unroll
    for (int g = 0; g < 4; g++){
      acc[g][0] = __builtin_amdgcn_mfma_f32_16x16x32_bf16(a0, B[kt][g], acc[g][0], 0, 0, 0);
      acc[g][1] = __builtin_amdgcn_mfma_f32_16x16x32_bf16(a1, B[kt][g], acc[g][1], 0, 0, 0);
    }
  }
}

__device__ __forceinline__ void cell0_finish(const unsigned short* __restrict__ A,
                                             const bf16x8 (&B)[3][4],
                                             f32x4 (&acc)[4][2],
                                             float (&c)[8],
                                             unsigned short (&hout)[8],
                                             int lane){
  bf16x8 a0 = *(const bf16x8*)(A +        lane * 8);
  bf16x8 a1 = *(const bf16x8*)(A + 1536 + lane * 8);
#pragma unroll
  for (int g = 0; g < 4; g++){
    acc[g][0] = __builtin_amdgcn_mfma_f32_16x16x32_bf16(a0, B[0][g], acc[g][0], 0, 0, 0);
    acc[g][1] = __builtin_amdgcn_mfma_f32_16x16x32_bf16(a1, B[0][g], acc[g][1], 0, 0, 0);
  }
  cell_act(acc, c, hout);
}

// ---------------------------------------------------------------------------
// Main: one block = 32 batch rows. Encoder: 1 barrier/step (layer-skewed).
// Decoder: 3 barriers/step with cell0 SPLIT across barNext — kt1,2 issue in
// the projC window (filling the w>=2 idle slot and overlapping projC), only
// kt0 (m) + activation remain after the barrier. projC computes pred^T via
// mfma(Wout, h1-bytes) (self-transposing LDS read), float4 trg add + out
// store, then mfma(W_in, x^T) -> next m, one ds_write_b64. All barriers
// LDS-only (bar_lds).
// ---------------------------------------------------------------------------
__global__ __launch_bounds__(256, 2)
void lstm_main(const float* __restrict__ src, const float* __restrict__ trg,
               const float* __restrict__ W_in, const float* __restrict__ b_in,
               const float* __restrict__ eb0, const float* __restrict__ eb1,
               const float* __restrict__ db0, const float* __restrict__ db1,
               const float* __restrict__ bout,
               const unsigned short* __restrict__ pw,
               float* __restrict__ out){
  __shared__ __align__(16) unsigned short A0[2][2][1536];   // ping-pong, 2 row-subtiles, K=96
  __shared__ __align__(16) unsigned short A1[2][2][2048];   // K=128
  __shared__ __align__(16) float xsrc[2][128];              // encoder x ping-pong (32 rows x 4)
  __shared__ __align__(16) unsigned short sWoutF[1024];     // W_out frags (A- and B-usable)
  __shared__ __align__(16) unsigned short sWinF[512];       // W_in A-frag (K=4 padded to 32)

  const int tid  = threadIdx.x;
  const int lane = tid & 63;
  const int w    = tid >> 6;
  const int quad = lane >> 4;
  const int l16  = lane & 15;
  const int j    = 16 * w + l16;
  const int rowg0 = blockIdx.x * 32;
  const int mm   = tid & 15;                  // x-proj: this thread's m-unit
  const int xr   = tid >> 4;                  // x-proj: rows xr and xr+16

  // ---- staging ----
  {
    uint4 z; z.x = z.y = z.z = z.w = 0u;
    uint4* a0p = (uint4*)A0;                  // 768 uint4
    uint4* a1p = (uint4*)A1;                  // 1024 uint4
    for (int i = tid; i < 768;  i += 256) a0p[i] = z;
    for (int i = tid; i < 1024; i += 256) a1p[i] = z;
    if (tid < 128) ((uint4*)sWoutF)[tid] = ((const uint4*)pw)[224 * 64 + tid];
    if (tid < 64){                            // W_in A-frag: lane<16, jj<4 = W_in[l][jj]
      unsigned short v[8] = {0,0,0,0,0,0,0,0};
      if (tid < 16){
#pragma unroll
        for (int jj = 0; jj < 4; jj++) v[jj] = f2bf(W_in[tid * 4 + jj]);
      }
      uint4 o;
      o.x = (unsigned)v[0] | ((unsigned)v[1] << 16);
      o.y = (unsigned)v[2] | ((unsigned)v[3] << 16);
      o.z = o.w = 0u;
      ((uint4*)sWinF)[tid] = o;
    }
    if (tid < 128) xsrc[0][tid] = src[(long)(rowg0 + (tid >> 2)) * 256 + (tid & 3)];
  }
  const float4 wv = *(const float4*)&W_in[mm * 4];
  const float  bin = b_in[mm];

  bf16x8 B0[3][4], B1[4][4];
  float bias0[4], bias1[4];
  float c0[8] = {0,0,0,0,0,0,0,0}, c1[8] = {0,0,0,0,0,0,0,0};
  load_frags(pw, 0, 48, w, lane, B0, B1);
#pragma unroll
  for (int g = 0; g < 4; g++){
    int n = 64*g + j;
    float s = (g == 2) ? -2.88539008f : -1.44269504f;   // match weight pre-scale
    bias0[g] = eb0[n] * s; bias1[g] = eb1[n] * s;
  }
  bar_lds();

  unsigned short h0r[8], h1r[8];
  const int xoff = (xr | ((mm >> 3) << 4)) * 8 + (mm & 7);   // A-layout slot for k=mm

  // ================= encoder: 1 barrier/step (cell1 skewed by 1) =================
  for (int t = 0; t < 64; t++){
    int cur = t & 1, nxt = cur ^ 1;
    float xv;
    if (tid < 128)
      xv = src[(long)(rowg0 + (tid >> 2)) * 256 + ((t == 63 ? 63 : t + 1) << 2) + (tid & 3)];
    { // x-projection for rows xr, xr+16
      float4 x0 = *(const float4*)&xsrc[cur][xr * 4];
      float4 x1 = *(const float4*)&xsrc[cur][(xr + 16) * 4];
      float m0 = bin + x0.x*wv.x + x0.y*wv.y + x0.z*wv.z + x0.w*wv.w;
      float m1 = bin + x1.x*wv.x + x1.y*wv.y + x1.z*wv.z + x1.w*wv.w;
      A0[cur][0][xoff] = f2bf(m0);
      A0[cur][1][xoff] = f2bf(m1);
    }
    if (tid < 128) xsrc[nxt][tid] = xv;
    bar_lds();
    // cell0(t)
    cell_compute<3, 1536>(&A0[cur][0][0], B0, bias0, c0, h0r, lane);
#pragma unroll
    for (int rt = 0; rt < 2; rt++){
      write_h(&A0[nxt][rt][0], 32 + j, quad, h0r + rt * 4);   // recurrent h0
      write_h(&A1[cur][rt][0],      j, quad, h0r + rt * 4);   // feed layer 1
    }
    // cell1(t-1) — inputs written during iter t-1, visible since barrier above
    if (t > 0){
      cell_compute<4, 2048>(&A1[nxt][0][0], B1, bias1, c1, h1r, lane);
#pragma unroll
      for (int rt = 0; rt < 2; rt++)
        write_h(&A1[cur][rt][0], 64 + j, quad, h1r + rt * 4); // recurrent h1
    }
  }
  bar_lds();
  // flush cell1(63): reads A1[1], writes recurrent into A1[0] for decoder t=0
  cell_compute<4, 2048>(&A1[1][0][0], B1, bias1, c1, h1r, lane);
#pragma unroll
  for (int rt = 0; rt < 2; rt++)
    write_h(&A1[0][rt][0], 64 + j, quad, h1r + rt * 4);
  // NOTE: A0[0] k=32..95 holds h0_enc(63) = decoder L0's initial hidden (matches ref init)

  // ================= decoder (3 barriers/step, cell0 split) =================
  load_frags(pw, 112, 160, w, lane, B0, B1);
#pragma unroll
  for (int g = 0; g < 4; g++){
    int n = 64*g + j;
    float s = (g == 2) ? -2.88539008f : -1.44269504f;
    bias0[g] = db0[n] * s; bias1[g] = db1[n] * s;
  }
  // per-lane constants for the transposed projection chain
  const float4 bq   = *(const float4*)&b_in[quad * 4];      // b_in[quad*4+e] (C-init of m^T)
  f32x4 boT = {0.0f, 0.0f, 0.0f, 0.0f};
  if (quad == 0){
    float4 b4 = *(const float4*)bout;
    boT[0] = b4.x; boT[1] = b4.y; boT[2] = b4.z; boT[3] = b4.w;
  }
  { // m(0) = trg(:,0) @ W_in^T + b_in  ->  A0[0] m-slots
    float4 x0 = *(const float4*)&trg[(long)(rowg0 + xr) * 256];
    float4 x1 = *(const float4*)&trg[(long)(rowg0 + xr + 16) * 256];
    float m0 = bin + x0.x*wv.x + x0.y*wv.y + x0.z*wv.z + x0.w*wv.w;
    float m1 = bin + x1.x*wv.x + x1.y*wv.y + x1.z*wv.z + x1.w*wv.w;
    A0[0][0][xoff] = f2bf(m0);
    A0[0][1][xoff] = f2bf(m1);
  }
  bar_lds();

  f32x4 accP[4][2];
  cell0_start(&A0[0][0][0], B0, bias0, accP, lane);   // h0-slots of A0[0] (enc h0(63))

  for (int t = 0; t < 64; t++){
    int cur = t & 1, nxt = cur ^ 1;
    float4 tpreT = {0.0f, 0.0f, 0.0f, 0.0f};
    if (w < 2 && quad == 0)                  // row = w*16+l16, comps t*4..t*4+3 (float4)
      tpreT = *(const float4*)&trg[(long)(rowg0 + w * 16 + l16) * 256 + t * 4];
    // finish cell0(t): kt0 (m from projC(t-1)) + activation
    cell0_finish(&A0[cur][0][0], B0, accP, c0, h0r, lane);
#pragma unroll
    for (int rt = 0; rt < 2; rt++){
      write_h(&A0[nxt][rt][0], 32 + j, quad, h0r + rt * 4);   // recurrent h0 for t+1
      write_h(&A1[cur][rt][0],      j, quad, h0r + rt * 4);   // feed layer 1
    }
    bar_lds();                             // barB: h0 visible
    cell_compute<4, 2048>(&A1[cur][0][0], B1, bias1, c1, h1r, lane);
#pragma unroll
    for (int rt = 0; rt < 2; rt++)
      write_h(&A1[nxt][rt][0], 64 + j, quad, h1r + rt * 4);   // recurrent h1 for t+1
    bar_lds();                             // barC: h1(t) visible
    // start cell0(t+1): kt1,2 read A0[nxt] h0-slots (written pre-barB) — runs
    // in the projC window, filling the w>=2 idle slot.
    cell0_start(&A0[nxt][0][0], B0, bias0, accP, lane);
    if (w < 2){                            // projC (wave w = row-subtile w)
      const unsigned short* Ah = &A1[nxt][w][0];
      // self-transposing reads: these bytes are the B-frag of h1^T
      bf16x8 hb0 = *(const bf16x8*)(Ah + (2 * 64 + lane) * 8);
      bf16x8 hb1 = *(const bf16x8*)(Ah + (3 * 64 + lane) * 8);
      bf16x8 wa0 = *(const bf16x8*)(sWoutF + lane * 8);       // Wout as A-frag
      bf16x8 wa1 = *(const bf16x8*)(sWoutF + 512 + lane * 8);
      f32x4 po = boT;                                         // pred^T = Wout @ h1^T
      po = __builtin_amdgcn_mfma_f32_16x16x32_bf16(wa0, hb0, po, 0, 0, 0);
      po = __builtin_amdgcn_mfma_f32_16x16x32_bf16(wa1, hb1, po, 0, 0, 0);
      // quad0 lane l16 holds x[row=l16][e] = po[e] + trg
      unsigned int xp0 = 0u, xp1 = 0u;
      if (quad == 0){
        float4 xv;
        xv.x = po[0] + tpreT.x;  xv.y = po[1] + tpreT.y;
        xv.z = po[2] + tpreT.z;  xv.w = po[3] + tpreT.w;
        *(float4*)&out[(long)(rowg0 + w * 16 + l16) * 256 + t * 4] = xv;
        xp0 = (unsigned)f2bf(xv.x) | ((unsigned)f2bf(xv.y) << 16);
        xp1 = (unsigned)f2bf(xv.z) | ((unsigned)f2bf(xv.w) << 16);
      }
      uint4 xb_u; xb_u.x = xp0; xb_u.y = xp1; xb_u.z = 0u; xb_u.w = 0u;
      bf16x8 xb = __builtin_bit_cast(bf16x8, xb_u);           // B-frag of x^T (K=4 pad 32)
      bf16x8 wi = *(const bf16x8*)(sWinF + lane * 8);         // W_in as A-frag
      f32x4 pm = {bq.x, bq.y, bq.z, bq.w};                    // m^T = W_in @ x^T + b_in
      pm = __builtin_amdgcn_mfma_f32_16x16x32_bf16(wi, xb, pm, 0, 0, 0);
      // lane holds m[row=l16][mm=quad*4+e]; 4 consecutive halfwords in A-layout
      unsigned int mp0 = (unsigned)f2bf(pm[0]) | ((unsigned)f2bf(pm[1]) << 16);
      unsigned int mp1 = (unsigned)f2bf(pm[2]) | ((unsigned)f2bf(pm[3]) << 16);
      uint2 mw; mw.x = mp0; mw.y = mp1;
      *(uint2*)&A0[nxt][w][(l16 | ((quad >> 1) << 4)) * 8 + (quad & 1) * 4] = mw;
    }
    bar_lds();                             // barNext: A0[nxt] (m + h0) ready
  }
}

extern "C" void kernel_launch(void* const* d_in, const int* in_sizes, int n_in,
                              void* d_out, int out_size, void* d_ws, size_t ws_size,
                              hipStream_t stream){
  (void)n_in; (void)out_size; (void)ws_size;
  const float* src   = (const float*)d_in[0];
  const float* trg   = (const float*)d_in[1];
  const float* W_in  = (const float*)d_in[2];
  const float* b_in  = (const float*)d_in[3];
  const float* eWih0 = (const float*)d_in[4];
  const float* eWhh0 = (const float*)d_in[5];
  const float* eb0   = (const float*)d_in[6];
  const float* eWih1 = (const float*)d_in[7];
  const float* eWhh1 = (const float*)d_in[8];
  const float* eb1   = (const float*)d_in[9];
  const float* dWih0 = (const float*)d_in[10];
  const float* dWhh0 = (const float*)d_in[11];
  const float* db0   = (const float*)d_in[12];
  const float* dWih1 = (const float*)d_in[13];
  const float* dWhh1 = (const float*)d_in[14];
  const float* db1   = (const float*)d_in[15];
  const float* Wout  = (const float*)d_in[16];
  const float* bout  = (const float*)d_in[17];
  unsigned short* pw = (unsigned short*)d_ws;          // needs 231,424 bytes

  pack_weights<<<57, 256, 0, stream>>>(eWih0, eWhh0, eWih1, eWhh1,
                                       dWih0, dWhh0, dWih1, dWhh1, Wout, pw);

  int B    = in_sizes[0] / 256;                        // S*I = 256
  int nblk = B / 32;
  lstm_main<<<nblk, 256, 0, stream>>>(src, trg, W_in, b_in, eb0, eb1, db0, db1,
                                      bout, pw, (float*)d_out);
}